// Round 7
// baseline (287.964 us; speedup 1.0000x reference)
//
#include <hip/hip_runtime.h>

// ContextAttentionBlock fused kernel for gfx950.
// Per (b,h) row-strip (2048 strips of [128x128]): everything in LDS with
// bf16 MFMA (32x32x16), fp32 accum. Shortcut conv folded into the output
// projection (w_sc @ Wo1 precomputed).
//
// Occupancy/VGPR notes (measured R1-R6):
//  - hipcc allocates VGPR = 65536/blockDim regardless of launch_bounds arg2
//    (512thr->128, 1024thr->64). We must FIT in 128.
//  - R6: #pragma unroll 2 on kk loops killed the spills (FETCH 502->102MB,
//    dur 370->242us). R7: unroll 4 widens the load window (~48 regs in
//    flight, worst-case live ~124 < 128) to cut latency serialization.
//  - LDS rotation: FPT region is dead after phase C, so next strip's x is
//    staged there; XB/FPT roles swap each iteration.

typedef __bf16 bf16x8 __attribute__((ext_vector_type(8)));
typedef float f32x16 __attribute__((ext_vector_type(16)));
typedef unsigned short u16x4 __attribute__((ext_vector_type(4)));
typedef unsigned short ushort_t;

__device__ __forceinline__ unsigned short f2bf(float x) {
    unsigned int u = __float_as_uint(x);
    u += 0x7fffu + ((u >> 16) & 1u);   // round-to-nearest-even
    return (unsigned short)(u >> 16);
}
__device__ __forceinline__ float bf2f(unsigned short h) {
    return __uint_as_float(((unsigned int)h) << 16);
}
// byte offset inside a [128][128] bf16 buffer (256 B rows).
// XOR of row bits into byte-offset bits 4..7 spreads 32-consecutive-row
// column accesses over 16 distinct 16B slots -> ~2-way bank aliasing.
// (R2: conflicts 13.1M -> 2.6M vs the (row&7) variant.)
__device__ __forceinline__ int swz(int row, int cb) {
    return (row << 8) + (cb ^ ((row & 15) << 4));
}
__device__ __forceinline__ float sigm(float t) {
    return 1.0f / (1.0f + __expf(-t));
}

// ---------------- pre-pass 1: combined shortcut weight -----------------
__global__ void prep_combine(const float* __restrict__ w_sc,
                             const float* __restrict__ b_sc,
                             const float* __restrict__ w_out,
                             const float* __restrict__ b_out,
                             float* __restrict__ wsc2,
                             float* __restrict__ bout2) {
    int k = blockIdx.x;      // 0..127
    int n = threadIdx.x;     // 0..127
    float acc = 0.f;
    for (int c = 0; c < 128; ++c)
        acc += w_sc[k * 128 + c] * w_out[(128 + c) * 128 + n];
    wsc2[k * 128 + n] = acc;
    if (k == 0) {
        float b = b_out[n];
        for (int c = 0; c < 128; ++c)
            b += b_sc[c] * w_out[(128 + c) * 128 + n];
        bout2[n] = b;
    }
}

// ---------------- pre-pass 2: pack weights into MFMA B-frag order ------
__global__ void prep_pack(const float* __restrict__ wth,
                          const float* __restrict__ wph,
                          const float* __restrict__ wg,
                          const float* __restrict__ wout,
                          const float* __restrict__ wsc2,
                          ushort_t* __restrict__ packs) {
    int m = blockIdx.x;
    const float* src;
    int rowoff = 0;
    if (m == 0) src = wth;
    else if (m == 1) src = wph;
    else if (m == 2) src = wg;
    else if (m == 3) { src = wout; rowoff = 0; }
    else if (m == 4) { src = wout; rowoff = 256; }
    else src = wsc2;
    ushort_t* dst = packs + m * 16384;
    for (int i = threadIdx.x; i < 16384; i += blockDim.x) {
        int j = i & 7;
        int lane = (i >> 3) & 63;
        int kk = (i >> 9) & 7;
        int nt = i >> 12;
        int k = kk * 16 + ((lane >> 5) << 3) + j;
        int n = nt * 32 + (lane & 31);
        dst[i] = f2bf(src[(rowoff + k) * 128 + n]);
    }
}

// ---------------- main fused kernel ------------------------------------
#define FPB 32768
#define FGT 98304

__global__ __launch_bounds__(512, 2)
void cab_main(const float* __restrict__ x,
              const float* __restrict__ b_theta,
              const float* __restrict__ b_phi,
              const float* __restrict__ b_g,
              const ushort_t* __restrict__ packs,
              const float* __restrict__ bout2,
              float* __restrict__ out,
              int nstrips, int spb) {
    __shared__ __align__(16) char lds[131072];

    const int tid = threadIdx.x;
    const int l   = tid & 63;
    const int wv  = tid >> 6;          // 0..7
    const int ct  = wv & 3;            // tile col (0..3)
    const int rt0 = (wv >> 2) << 1;    // tile rows rt0, rt0+1
    const int ln  = l & 31;
    const int lh  = l >> 5;
    const int colg = ct * 32 + ln;     // this wave's output column

    const ushort_t* pTH = packs;
    const ushort_t* pPH = packs + 16384;
    const ushort_t* pG  = packs + 2 * 16384;
    const ushort_t* pO0 = packs + 3 * 16384;
    const ushort_t* pO2 = packs + 4 * 16384;
    const ushort_t* pS2 = packs + 5 * 16384;

    const float biasTH = b_theta[colg];
    const float biasPH = b_phi[colg];
    const float biasG  = b_g[colg];
    const float biasO  = bout2[colg];

    const int s0 = blockIdx.x * spb;
    if (s0 >= nstrips) return;
    const float4* x4 = (const float4*)x;

    // staging geometry: idx = q*512+tid covers float4 idx -> row=idx>>5,
    // cb = (tid&31)*8 bytes; chunk c covers rows c*64..c*64+63
    const int srow = tid >> 5;          // 0..15
    const int scb  = (tid & 31) * 8;    // byte col

    float4 pf[4];

    // initial full stage of strip s0 into region 0
    {
        long base = (long)s0 * 4096;
#pragma unroll
        for (int c = 0; c < 2; ++c) {
#pragma unroll
            for (int q = 0; q < 4; ++q) pf[q] = x4[base + (c * 4 + q) * 512 + tid];
#pragma unroll
            for (int q = 0; q < 4; ++q) {
                int row = c * 64 + q * 16 + srow;
                u16x4 v;
                v[0] = f2bf(pf[q].x); v[1] = f2bf(pf[q].y);
                v[2] = f2bf(pf[q].z); v[3] = f2bf(pf[q].w);
                *(u16x4*)(lds + swz(row, scb)) = v;
            }
        }
    }
    __syncthreads();

    for (int it = 0; it < spb; ++it) {
        const int s = s0 + it;
        // rotating roles: XB holds current x; FPT region doubles as next-XB
        const int XBo  = (it & 1) ? 65536 : 0;
        const int FPTo = 65536 - XBo;
        f32x16 accA, accB;

        // ===== B1: f_phi = xb @ w_phi + b  -> FPB (row-major) + FPT ([c][w])
#pragma unroll
        for (int i = 0; i < 16; ++i) { accA[i] = 0.f; accB[i] = 0.f; }
#pragma unroll 4
        for (int kk = 0; kk < 8; ++kk) {
            bf16x8 b  = *(const bf16x8*)(pPH + (((ct * 8 + kk) * 64 + l) << 3));
            bf16x8 a0 = *(const bf16x8*)(lds + XBo + swz(rt0 * 32 + ln,      kk * 32 + lh * 16));
            bf16x8 a1 = *(const bf16x8*)(lds + XBo + swz(rt0 * 32 + 32 + ln, kk * 32 + lh * 16));
            accA = __builtin_amdgcn_mfma_f32_32x32x16_bf16(a0, b, accA, 0, 0, 0);
            accB = __builtin_amdgcn_mfma_f32_32x32x16_bf16(a1, b, accB, 0, 0, 0);
        }
#pragma unroll
        for (int t2 = 0; t2 < 2; ++t2) {
            const f32x16& acc = t2 ? accB : accA;
            int m0 = (rt0 + t2) * 32;
#pragma unroll
            for (int r = 0; r < 16; ++r) {
                int row = m0 + (r & 3) + ((r >> 2) << 3) + (lh << 2);
                *(ushort_t*)(lds + FPB + swz(row, colg * 2)) = f2bf(acc[r] + biasPH);
            }
#pragma unroll
            for (int q = 0; q < 4; ++q) {
                int w0 = m0 + (q << 3) + (lh << 2);
                u16x4 v;
#pragma unroll
                for (int e = 0; e < 4; ++e) v[e] = f2bf(acc[q * 4 + e] + biasPH);
                *(u16x4*)(lds + FPTo + swz(colg, w0 * 2)) = v;
            }
        }

        // ===== B2: f_g = xb @ w_g + b -> FGT ([c][w])
#pragma unroll
        for (int i = 0; i < 16; ++i) { accA[i] = 0.f; accB[i] = 0.f; }
#pragma unroll 4
        for (int kk = 0; kk < 8; ++kk) {
            bf16x8 b  = *(const bf16x8*)(pG + (((ct * 8 + kk) * 64 + l) << 3));
            bf16x8 a0 = *(const bf16x8*)(lds + XBo + swz(rt0 * 32 + ln,      kk * 32 + lh * 16));
            bf16x8 a1 = *(const bf16x8*)(lds + XBo + swz(rt0 * 32 + 32 + ln, kk * 32 + lh * 16));
            accA = __builtin_amdgcn_mfma_f32_32x32x16_bf16(a0, b, accA, 0, 0, 0);
            accB = __builtin_amdgcn_mfma_f32_32x32x16_bf16(a1, b, accB, 0, 0, 0);
        }
#pragma unroll
        for (int t2 = 0; t2 < 2; ++t2) {
            const f32x16& acc = t2 ? accB : accA;
            int m0 = (rt0 + t2) * 32;
#pragma unroll
            for (int q = 0; q < 4; ++q) {
                int w0 = m0 + (q << 3) + (lh << 2);
                u16x4 v;
#pragma unroll
                for (int e = 0; e < 4; ++e) v[e] = f2bf(acc[q * 4 + e] + biasG);
                *(u16x4*)(lds + FGT + swz(colg, w0 * 2)) = v;
            }
        }
        __syncthreads();   // (1) FPB/FPT/FGT ready

        // issue chunk0 of next strip's x (latency hidden by D/V/B3/C)
        if (it + 1 < spb) {
            long base = (long)(s + 1) * 4096;
#pragma unroll
            for (int q = 0; q < 4; ++q) pf[q] = x4[base + q * 512 + tid];
        }

        // ===== D: v-logits  D[j][i] = sum_w fp[w][j] * fg[w][i]
#pragma unroll
        for (int i = 0; i < 16; ++i) { accA[i] = 0.f; accB[i] = 0.f; }
#pragma unroll 4
        for (int kk = 0; kk < 8; ++kk) {
            bf16x8 b  = *(const bf16x8*)(lds + FGT + swz(colg, kk * 32 + lh * 16));
            bf16x8 a0 = *(const bf16x8*)(lds + FPTo + swz(rt0 * 32 + ln,      kk * 32 + lh * 16));
            bf16x8 a1 = *(const bf16x8*)(lds + FPTo + swz(rt0 * 32 + 32 + ln, kk * 32 + lh * 16));
            accA = __builtin_amdgcn_mfma_f32_32x32x16_bf16(a0, b, accA, 0, 0, 0);
            accB = __builtin_amdgcn_mfma_f32_32x32x16_bf16(a1, b, accB, 0, 0, 0);
        }
        __syncthreads();   // (2) all D reads of FPT/FGT done

        // V epilogue: V[i][j] = sigm(D[j][i]) * x[i][j]  -> overwrite FGT
#pragma unroll
        for (int t2 = 0; t2 < 2; ++t2) {
            const f32x16& acc = t2 ? accB : accA;
            int m0 = (rt0 + t2) * 32;
#pragma unroll
            for (int q = 0; q < 4; ++q) {
                int j0 = m0 + (q << 3) + (lh << 2);
                u16x4 xv = *(const u16x4*)(lds + XBo + swz(colg, j0 * 2));
                u16x4 v;
#pragma unroll
                for (int e = 0; e < 4; ++e)
                    v[e] = f2bf(sigm(acc[q * 4 + e]) * bf2f(xv[e]));
                *(u16x4*)(lds + FGT + swz(colg, j0 * 2)) = v;
            }
        }

        // ===== B3: f_theta = xb @ w_theta + b -> FPT slot (row-major "ftb")
#pragma unroll
        for (int i = 0; i < 16; ++i) { accA[i] = 0.f; accB[i] = 0.f; }
#pragma unroll 4
        for (int kk = 0; kk < 8; ++kk) {
            bf16x8 b  = *(const bf16x8*)(pTH + (((ct * 8 + kk) * 64 + l) << 3));
            bf16x8 a0 = *(const bf16x8*)(lds + XBo + swz(rt0 * 32 + ln,      kk * 32 + lh * 16));
            bf16x8 a1 = *(const bf16x8*)(lds + XBo + swz(rt0 * 32 + 32 + ln, kk * 32 + lh * 16));
            accA = __builtin_amdgcn_mfma_f32_32x32x16_bf16(a0, b, accA, 0, 0, 0);
            accB = __builtin_amdgcn_mfma_f32_32x32x16_bf16(a1, b, accB, 0, 0, 0);
        }
#pragma unroll
        for (int t2 = 0; t2 < 2; ++t2) {
            const f32x16& acc = t2 ? accB : accA;
            int m0 = (rt0 + t2) * 32;
#pragma unroll
            for (int r = 0; r < 16; ++r) {
                int row = m0 + (r & 3) + ((r >> 2) << 3) + (lh << 2);
                *(ushort_t*)(lds + FPTo + swz(row, colg * 2)) = f2bf(acc[r] + biasTH);
            }
        }
        __syncthreads();   // (3) V + ftb ready

        // ===== C: h-logits  D[v][w] = sum_c ft[v][c] * fp[w][c]
#pragma unroll
        for (int i = 0; i < 16; ++i) { accA[i] = 0.f; accB[i] = 0.f; }
#pragma unroll 4
        for (int kk = 0; kk < 8; ++kk) {
            bf16x8 b  = *(const bf16x8*)(lds + FPB + swz(colg, kk * 32 + lh * 16));
            bf16x8 a0 = *(const bf16x8*)(lds + FPTo + swz(rt0 * 32 + ln,      kk * 32 + lh * 16));
            bf16x8 a1 = *(const bf16x8*)(lds + FPTo + swz(rt0 * 32 + 32 + ln, kk * 32 + lh * 16));
            accA = __builtin_amdgcn_mfma_f32_32x32x16_bf16(a0, b, accA, 0, 0, 0);
            accB = __builtin_amdgcn_mfma_f32_32x32x16_bf16(a1, b, accB, 0, 0, 0);
        }
        __syncthreads();   // (4) all C reads of FPB/FPT done; FPT region now free

        // write chunk0 of next x into FPT region (= next iteration's XB)
        if (it + 1 < spb) {
#pragma unroll
            for (int q = 0; q < 4; ++q) {
                int row = q * 16 + srow;     // rows 0..63
                u16x4 v;
                v[0] = f2bf(pf[q].x); v[1] = f2bf(pf[q].y);
                v[2] = f2bf(pf[q].z); v[3] = f2bf(pf[q].w);
                *(u16x4*)(lds + FPTo + swz(row, scb)) = v;
            }
            // issue chunk1 loads (latency hidden by H epilogue + E)
            long base = (long)(s + 1) * 4096;
#pragma unroll
            for (int q = 0; q < 4; ++q) pf[q] = x4[base + (4 + q) * 512 + tid];
        }

        // H epilogue: H[w][v] = sigm(D[v][w]) * x[w][v] -> overwrite FPB
#pragma unroll
        for (int t2 = 0; t2 < 2; ++t2) {
            const f32x16& acc = t2 ? accB : accA;
            int m0 = (rt0 + t2) * 32;
#pragma unroll
            for (int q = 0; q < 4; ++q) {
                int v0 = m0 + (q << 3) + (lh << 2);
                u16x4 xv = *(const u16x4*)(lds + XBo + swz(colg, v0 * 2));
                u16x4 v;
#pragma unroll
                for (int e = 0; e < 4; ++e)
                    v[e] = f2bf(sigm(acc[q * 4 + e]) * bf2f(xv[e]));
                *(u16x4*)(lds + FPB + swz(colg, v0 * 2)) = v;
            }
        }
        __syncthreads();   // (5) H ready

        // ===== E: out = H @ Wo0 + V @ Wo2 + xb @ Wsc2 + bout2
        //        (three clean 8-loops; acc carries across all 24 steps)
#pragma unroll
        for (int i = 0; i < 16; ++i) { accA[i] = 0.f; accB[i] = 0.f; }
#pragma unroll 4
        for (int kk = 0; kk < 8; ++kk) {
            bf16x8 b  = *(const bf16x8*)(pO0 + (((ct * 8 + kk) * 64 + l) << 3));
            bf16x8 a0 = *(const bf16x8*)(lds + FPB + swz(rt0 * 32 + ln,      kk * 32 + lh * 16));
            bf16x8 a1 = *(const bf16x8*)(lds + FPB + swz(rt0 * 32 + 32 + ln, kk * 32 + lh * 16));
            accA = __builtin_amdgcn_mfma_f32_32x32x16_bf16(a0, b, accA, 0, 0, 0);
            accB = __builtin_amdgcn_mfma_f32_32x32x16_bf16(a1, b, accB, 0, 0, 0);
        }
#pragma unroll 4
        for (int kk = 0; kk < 8; ++kk) {
            bf16x8 b  = *(const bf16x8*)(pO2 + (((ct * 8 + kk) * 64 + l) << 3));
            bf16x8 a0 = *(const bf16x8*)(lds + FGT + swz(rt0 * 32 + ln,      kk * 32 + lh * 16));
            bf16x8 a1 = *(const bf16x8*)(lds + FGT + swz(rt0 * 32 + 32 + ln, kk * 32 + lh * 16));
            accA = __builtin_amdgcn_mfma_f32_32x32x16_bf16(a0, b, accA, 0, 0, 0);
            accB = __builtin_amdgcn_mfma_f32_32x32x16_bf16(a1, b, accB, 0, 0, 0);
        }
#pragma unroll 4
        for (int kk = 0; kk < 8; ++kk) {
            bf16x8 b  = *(const bf16x8*)(pS2 + (((ct * 8 + kk) * 64 + l) << 3));
            bf16x8 a0 = *(const bf16x8*)(lds + XBo + swz(rt0 * 32 + ln,      kk * 32 + lh * 16));
            bf16x8 a1 = *(const bf16x8*)(lds + XBo + swz(rt0 * 32 + 32 + ln, kk * 32 + lh * 16));
            accA = __builtin_amdgcn_mfma_f32_32x32x16_bf16(a0, b, accA, 0, 0, 0);
            accB = __builtin_amdgcn_mfma_f32_32x32x16_bf16(a1, b, accB, 0, 0, 0);
        }
        {
            long obase = (long)s * 16384;
#pragma unroll
            for (int t2 = 0; t2 < 2; ++t2) {
                const f32x16& acc = t2 ? accB : accA;
                int m0 = (rt0 + t2) * 32;
#pragma unroll
                for (int r = 0; r < 16; ++r) {
                    int row = m0 + (r & 3) + ((r >> 2) << 3) + (lh << 2);
                    out[obase + row * 128 + colg] = acc[r] + biasO;
                }
            }
        }

        // write chunk1 of next x into FPT region (rows 64..127)
        if (it + 1 < spb) {
#pragma unroll
            for (int q = 0; q < 4; ++q) {
                int row = 64 + q * 16 + srow;
                u16x4 v;
                v[0] = f2bf(pf[q].x); v[1] = f2bf(pf[q].y);
                v[2] = f2bf(pf[q].z); v[3] = f2bf(pf[q].w);
                *(u16x4*)(lds + FPTo + swz(row, scb)) = v;
            }
        }
        __syncthreads();   // (6) E's XB reads + next-x staging done
    }
}

extern "C" void kernel_launch(void* const* d_in, const int* in_sizes, int n_in,
                              void* d_out, int out_size, void* d_ws, size_t ws_size,
                              hipStream_t stream) {
    const float* x       = (const float*)d_in[0];
    const float* w_theta = (const float*)d_in[1];
    const float* b_theta = (const float*)d_in[2];
    const float* w_phi   = (const float*)d_in[3];
    const float* b_phi   = (const float*)d_in[4];
    const float* w_g     = (const float*)d_in[5];
    const float* b_g     = (const float*)d_in[6];
    const float* w_sc    = (const float*)d_in[7];
    const float* b_sc    = (const float*)d_in[8];
    const float* w_out   = (const float*)d_in[9];
    const float* b_out   = (const float*)d_in[10];
    float* out = (float*)d_out;

    float* wsc2 = (float*)d_ws;                                        // 128*128 f32
    ushort_t* packs = (ushort_t*)((char*)d_ws + 65536);                // 6*16384 bf16
    float* bout2 = (float*)((char*)d_ws + 65536 + 6 * 16384 * 2);      // 128 f32

    int NS = in_sizes[0] / 16384;   // 2048 strips
    int spb = NS / 256;             // strips per block (8)
    if (spb < 1) spb = 1;
    int grid = (NS + spb - 1) / spb;

    prep_combine<<<128, 128, 0, stream>>>(w_sc, b_sc, w_out, b_out, wsc2, bout2);
    prep_pack<<<6, 256, 0, stream>>>(w_theta, w_phi, w_g, w_out, wsc2, packs);
    cab_main<<<grid, 512, 0, stream>>>(x, b_theta, b_phi, b_g, packs, bout2, out, NS, spb);
}

// Round 8
// 179.005 us; speedup vs baseline: 1.6087x; 1.6087x over previous
//
#include <hip/hip_runtime.h>

// ContextAttentionBlock fused kernel for gfx950.
// Per (b,h) row-strip (2048 strips of [128x128]): everything in LDS with
// bf16 MFMA (32x32x16), fp32 accum. Shortcut conv folded into the output
// projection (w_sc @ Wo1 precomputed).
//
// Occupancy/VGPR notes (measured R1-R7):
//  - hipcc allocates VGPR = 65536/blockDim (512->128, 1024->64); launch_bounds
//    arg2 is ignored beyond that. Must FIT the cap.
//  - unroll 2 on kk loops is the spill sweet spot (R6: FETCH 502->102MB);
//    unroll 4 re-spills (R7: 151MB, slower).
//  - R8: 1024 thr / 16 waves / ONE 32x32 tile per wave -> ~60 VGPR live,
//    4 waves/SIMD (2x TLP vs R6) to hide LDS/barrier/HBM latency.
//  - LDS rotation: FPT region is dead after phase C, so next strip's x is
//    staged there; XB/FPT roles swap each iteration.

typedef __bf16 bf16x8 __attribute__((ext_vector_type(8)));
typedef float f32x16 __attribute__((ext_vector_type(16)));
typedef unsigned short u16x4 __attribute__((ext_vector_type(4)));
typedef unsigned short ushort_t;

__device__ __forceinline__ unsigned short f2bf(float x) {
    unsigned int u = __float_as_uint(x);
    u += 0x7fffu + ((u >> 16) & 1u);   // round-to-nearest-even
    return (unsigned short)(u >> 16);
}
__device__ __forceinline__ float bf2f(unsigned short h) {
    return __uint_as_float(((unsigned int)h) << 16);
}
// byte offset inside a [128][128] bf16 buffer (256 B rows).
// XOR of row bits into byte-offset bits 4..7 spreads 32-consecutive-row
// column accesses over 16 distinct 16B slots -> ~2-way bank aliasing.
// (R2: conflicts 13.1M -> 2.6M vs the (row&7) variant.)
__device__ __forceinline__ int swz(int row, int cb) {
    return (row << 8) + (cb ^ ((row & 15) << 4));
}
__device__ __forceinline__ float sigm(float t) {
    return 1.0f / (1.0f + __expf(-t));
}

// ---------------- pre-pass 1: combined shortcut weight -----------------
__global__ void prep_combine(const float* __restrict__ w_sc,
                             const float* __restrict__ b_sc,
                             const float* __restrict__ w_out,
                             const float* __restrict__ b_out,
                             float* __restrict__ wsc2,
                             float* __restrict__ bout2) {
    int k = blockIdx.x;      // 0..127
    int n = threadIdx.x;     // 0..127
    float acc = 0.f;
    for (int c = 0; c < 128; ++c)
        acc += w_sc[k * 128 + c] * w_out[(128 + c) * 128 + n];
    wsc2[k * 128 + n] = acc;
    if (k == 0) {
        float b = b_out[n];
        for (int c = 0; c < 128; ++c)
            b += b_sc[c] * w_out[(128 + c) * 128 + n];
        bout2[n] = b;
    }
}

// ---------------- pre-pass 2: pack weights into MFMA B-frag order ------
__global__ void prep_pack(const float* __restrict__ wth,
                          const float* __restrict__ wph,
                          const float* __restrict__ wg,
                          const float* __restrict__ wout,
                          const float* __restrict__ wsc2,
                          ushort_t* __restrict__ packs) {
    int m = blockIdx.x;
    const float* src;
    int rowoff = 0;
    if (m == 0) src = wth;
    else if (m == 1) src = wph;
    else if (m == 2) src = wg;
    else if (m == 3) { src = wout; rowoff = 0; }
    else if (m == 4) { src = wout; rowoff = 256; }
    else src = wsc2;
    ushort_t* dst = packs + m * 16384;
    for (int i = threadIdx.x; i < 16384; i += blockDim.x) {
        int j = i & 7;
        int lane = (i >> 3) & 63;
        int kk = (i >> 9) & 7;
        int nt = i >> 12;
        int k = kk * 16 + ((lane >> 5) << 3) + j;
        int n = nt * 32 + (lane & 31);
        dst[i] = f2bf(src[(rowoff + k) * 128 + n]);
    }
}

// ---------------- main fused kernel ------------------------------------
#define FPB 32768
#define FGT 98304

__global__ __launch_bounds__(1024, 1)
void cab_main(const float* __restrict__ x,
              const float* __restrict__ b_theta,
              const float* __restrict__ b_phi,
              const float* __restrict__ b_g,
              const ushort_t* __restrict__ packs,
              const float* __restrict__ bout2,
              float* __restrict__ out,
              int nstrips, int spb) {
    __shared__ __align__(16) char lds[131072];

    const int tid = threadIdx.x;
    const int l   = tid & 63;
    const int wv  = tid >> 6;          // 0..15
    const int ct  = wv & 3;            // tile col (0..3)
    const int rt  = wv >> 2;           // tile row (0..3)
    const int ln  = l & 31;
    const int lh  = l >> 5;
    const int colg = ct * 32 + ln;     // this wave's output column
    const int m0   = rt * 32;          // this wave's output row base

    const ushort_t* pTH = packs;
    const ushort_t* pPH = packs + 16384;
    const ushort_t* pG  = packs + 2 * 16384;
    const ushort_t* pO0 = packs + 3 * 16384;
    const ushort_t* pO2 = packs + 4 * 16384;
    const ushort_t* pS2 = packs + 5 * 16384;

    const float biasTH = b_theta[colg];
    const float biasPH = b_phi[colg];
    const float biasG  = b_g[colg];
    const float biasO  = bout2[colg];

    const int s0 = blockIdx.x * spb;
    if (s0 >= nstrips) return;
    const float4* x4 = (const float4*)x;

    // staging geometry (1024 thr): idx = q*1024+tid -> row = q*32 + (tid>>5),
    // byte col = (tid&31)*8. Chunk c covers q = {2c, 2c+1} (rows c*64..c*64+63).
    const int srow = tid >> 5;          // 0..31
    const int scb  = (tid & 31) * 8;    // byte col

    float4 pf[2];

    // initial full stage of strip s0 into region 0
    {
        long base = (long)s0 * 4096;
#pragma unroll
        for (int c = 0; c < 2; ++c) {
#pragma unroll
            for (int q = 0; q < 2; ++q) pf[q] = x4[base + (c * 2 + q) * 1024 + tid];
#pragma unroll
            for (int q = 0; q < 2; ++q) {
                int row = (c * 2 + q) * 32 + srow;
                u16x4 v;
                v[0] = f2bf(pf[q].x); v[1] = f2bf(pf[q].y);
                v[2] = f2bf(pf[q].z); v[3] = f2bf(pf[q].w);
                *(u16x4*)(lds + swz(row, scb)) = v;
            }
        }
    }
    __syncthreads();

    for (int it = 0; it < spb; ++it) {
        const int s = s0 + it;
        // rotating roles: XB holds current x; FPT region doubles as next-XB
        const int XBo  = (it & 1) ? 65536 : 0;
        const int FPTo = 65536 - XBo;
        f32x16 acc;

        // ===== B1: f_phi = xb @ w_phi + b  -> FPB (row-major) + FPT ([c][w])
#pragma unroll
        for (int i = 0; i < 16; ++i) acc[i] = 0.f;
#pragma unroll 2
        for (int kk = 0; kk < 8; ++kk) {
            bf16x8 b = *(const bf16x8*)(pPH + (((ct * 8 + kk) * 64 + l) << 3));
            bf16x8 a = *(const bf16x8*)(lds + XBo + swz(m0 + ln, kk * 32 + lh * 16));
            acc = __builtin_amdgcn_mfma_f32_32x32x16_bf16(a, b, acc, 0, 0, 0);
        }
#pragma unroll
        for (int r = 0; r < 16; ++r) {
            int row = m0 + (r & 3) + ((r >> 2) << 3) + (lh << 2);
            *(ushort_t*)(lds + FPB + swz(row, colg * 2)) = f2bf(acc[r] + biasPH);
        }
#pragma unroll
        for (int q = 0; q < 4; ++q) {
            int w0 = m0 + (q << 3) + (lh << 2);
            u16x4 v;
#pragma unroll
            for (int e = 0; e < 4; ++e) v[e] = f2bf(acc[q * 4 + e] + biasPH);
            *(u16x4*)(lds + FPTo + swz(colg, w0 * 2)) = v;
        }

        // ===== B2: f_g = xb @ w_g + b -> FGT ([c][w])
#pragma unroll
        for (int i = 0; i < 16; ++i) acc[i] = 0.f;
#pragma unroll 2
        for (int kk = 0; kk < 8; ++kk) {
            bf16x8 b = *(const bf16x8*)(pG + (((ct * 8 + kk) * 64 + l) << 3));
            bf16x8 a = *(const bf16x8*)(lds + XBo + swz(m0 + ln, kk * 32 + lh * 16));
            acc = __builtin_amdgcn_mfma_f32_32x32x16_bf16(a, b, acc, 0, 0, 0);
        }
#pragma unroll
        for (int q = 0; q < 4; ++q) {
            int w0 = m0 + (q << 3) + (lh << 2);
            u16x4 v;
#pragma unroll
            for (int e = 0; e < 4; ++e) v[e] = f2bf(acc[q * 4 + e] + biasG);
            *(u16x4*)(lds + FGT + swz(colg, w0 * 2)) = v;
        }
        __syncthreads();   // (1) FPB/FPT/FGT ready

        // issue chunk0 of next strip's x (latency hidden by D/V/B3/C)
        if (it + 1 < spb) {
            long base = (long)(s + 1) * 4096;
#pragma unroll
            for (int q = 0; q < 2; ++q) pf[q] = x4[base + q * 1024 + tid];
        }

        // ===== D: v-logits  D[j][i] = sum_w fp[w][j] * fg[w][i]
#pragma unroll
        for (int i = 0; i < 16; ++i) acc[i] = 0.f;
#pragma unroll 2
        for (int kk = 0; kk < 8; ++kk) {
            bf16x8 b = *(const bf16x8*)(lds + FGT + swz(colg, kk * 32 + lh * 16));
            bf16x8 a = *(const bf16x8*)(lds + FPTo + swz(m0 + ln, kk * 32 + lh * 16));
            acc = __builtin_amdgcn_mfma_f32_32x32x16_bf16(a, b, acc, 0, 0, 0);
        }
        __syncthreads();   // (2) all D reads of FPT/FGT done

        // V epilogue: V[i][j] = sigm(D[j][i]) * x[i][j]  -> overwrite FGT
#pragma unroll
        for (int q = 0; q < 4; ++q) {
            int j0 = m0 + (q << 3) + (lh << 2);
            u16x4 xv = *(const u16x4*)(lds + XBo + swz(colg, j0 * 2));
            u16x4 v;
#pragma unroll
            for (int e = 0; e < 4; ++e)
                v[e] = f2bf(sigm(acc[q * 4 + e]) * bf2f(xv[e]));
            *(u16x4*)(lds + FGT + swz(colg, j0 * 2)) = v;
        }

        // ===== B3: f_theta = xb @ w_theta + b -> FPT slot (row-major "ftb")
#pragma unroll
        for (int i = 0; i < 16; ++i) acc[i] = 0.f;
#pragma unroll 2
        for (int kk = 0; kk < 8; ++kk) {
            bf16x8 b = *(const bf16x8*)(pTH + (((ct * 8 + kk) * 64 + l) << 3));
            bf16x8 a = *(const bf16x8*)(lds + XBo + swz(m0 + ln, kk * 32 + lh * 16));
            acc = __builtin_amdgcn_mfma_f32_32x32x16_bf16(a, b, acc, 0, 0, 0);
        }
#pragma unroll
        for (int r = 0; r < 16; ++r) {
            int row = m0 + (r & 3) + ((r >> 2) << 3) + (lh << 2);
            *(ushort_t*)(lds + FPTo + swz(row, colg * 2)) = f2bf(acc[r] + biasTH);
        }
        __syncthreads();   // (3) V + ftb ready

        // ===== C: h-logits  D[v][w] = sum_c ft[v][c] * fp[w][c]
#pragma unroll
        for (int i = 0; i < 16; ++i) acc[i] = 0.f;
#pragma unroll 2
        for (int kk = 0; kk < 8; ++kk) {
            bf16x8 b = *(const bf16x8*)(lds + FPB + swz(colg, kk * 32 + lh * 16));
            bf16x8 a = *(const bf16x8*)(lds + FPTo + swz(m0 + ln, kk * 32 + lh * 16));
            acc = __builtin_amdgcn_mfma_f32_32x32x16_bf16(a, b, acc, 0, 0, 0);
        }
        __syncthreads();   // (4) all C reads of FPB/FPT done; FPT region now free

        // write chunk0 of next x into FPT region (= next iteration's XB)
        if (it + 1 < spb) {
#pragma unroll
            for (int q = 0; q < 2; ++q) {
                int row = q * 32 + srow;     // rows 0..63
                u16x4 v;
                v[0] = f2bf(pf[q].x); v[1] = f2bf(pf[q].y);
                v[2] = f2bf(pf[q].z); v[3] = f2bf(pf[q].w);
                *(u16x4*)(lds + FPTo + swz(row, scb)) = v;
            }
            // issue chunk1 loads (latency hidden by H epilogue + E)
            long base = (long)(s + 1) * 4096;
#pragma unroll
            for (int q = 0; q < 2; ++q) pf[q] = x4[base + (2 + q) * 1024 + tid];
        }

        // H epilogue: H[w][v] = sigm(D[v][w]) * x[w][v] -> overwrite FPB
#pragma unroll
        for (int q = 0; q < 4; ++q) {
            int v0 = m0 + (q << 3) + (lh << 2);
            u16x4 xv = *(const u16x4*)(lds + XBo + swz(colg, v0 * 2));
            u16x4 v;
#pragma unroll
            for (int e = 0; e < 4; ++e)
                v[e] = f2bf(sigm(acc[q * 4 + e]) * bf2f(xv[e]));
            *(u16x4*)(lds + FPB + swz(colg, v0 * 2)) = v;
        }
        __syncthreads();   // (5) H ready

        // ===== E: out = H @ Wo0 + V @ Wo2 + xb @ Wsc2 + bout2
#pragma unroll
        for (int i = 0; i < 16; ++i) acc[i] = 0.f;
#pragma unroll 2
        for (int kk = 0; kk < 8; ++kk) {
            bf16x8 b = *(const bf16x8*)(pO0 + (((ct * 8 + kk) * 64 + l) << 3));
            bf16x8 a = *(const bf16x8*)(lds + FPB + swz(m0 + ln, kk * 32 + lh * 16));
            acc = __builtin_amdgcn_mfma_f32_32x32x16_bf16(a, b, acc, 0, 0, 0);
        }
#pragma unroll 2
        for (int kk = 0; kk < 8; ++kk) {
            bf16x8 b = *(const bf16x8*)(pO2 + (((ct * 8 + kk) * 64 + l) << 3));
            bf16x8 a = *(const bf16x8*)(lds + FGT + swz(m0 + ln, kk * 32 + lh * 16));
            acc = __builtin_amdgcn_mfma_f32_32x32x16_bf16(a, b, acc, 0, 0, 0);
        }
#pragma unroll 2
        for (int kk = 0; kk < 8; ++kk) {
            bf16x8 b = *(const bf16x8*)(pS2 + (((ct * 8 + kk) * 64 + l) << 3));
            bf16x8 a = *(const bf16x8*)(lds + XBo + swz(m0 + ln, kk * 32 + lh * 16));
            acc = __builtin_amdgcn_mfma_f32_32x32x16_bf16(a, b, acc, 0, 0, 0);
        }
        {
            long obase = (long)s * 16384;
#pragma unroll
            for (int r = 0; r < 16; ++r) {
                int row = m0 + (r & 3) + ((r >> 2) << 3) + (lh << 2);
                out[obase + row * 128 + colg] = acc[r] + biasO;
            }
        }

        // write chunk1 of next x into FPT region (rows 64..127)
        if (it + 1 < spb) {
#pragma unroll
            for (int q = 0; q < 2; ++q) {
                int row = 64 + q * 32 + srow;
                u16x4 v;
                v[0] = f2bf(pf[q].x); v[1] = f2bf(pf[q].y);
                v[2] = f2bf(pf[q].z); v[3] = f2bf(pf[q].w);
                *(u16x4*)(lds + FPTo + swz(row, scb)) = v;
            }
        }
        __syncthreads();   // (6) E's XB reads + next-x staging done
    }
}

extern "C" void kernel_launch(void* const* d_in, const int* in_sizes, int n_in,
                              void* d_out, int out_size, void* d_ws, size_t ws_size,
                              hipStream_t stream) {
    const float* x       = (const float*)d_in[0];
    const float* w_theta = (const float*)d_in[1];
    const float* b_theta = (const float*)d_in[2];
    const float* w_phi   = (const float*)d_in[3];
    const float* b_phi   = (const float*)d_in[4];
    const float* w_g     = (const float*)d_in[5];
    const float* b_g     = (const float*)d_in[6];
    const float* w_sc    = (const float*)d_in[7];
    const float* b_sc    = (const float*)d_in[8];
    const float* w_out   = (const float*)d_in[9];
    const float* b_out   = (const float*)d_in[10];
    float* out = (float*)d_out;

    float* wsc2 = (float*)d_ws;                                        // 128*128 f32
    ushort_t* packs = (ushort_t*)((char*)d_ws + 65536);                // 6*16384 bf16
    float* bout2 = (float*)((char*)d_ws + 65536 + 6 * 16384 * 2);      // 128 f32

    int NS = in_sizes[0] / 16384;   // 2048 strips
    int spb = NS / 256;             // strips per block (8)
    if (spb < 1) spb = 1;
    int grid = (NS + spb - 1) / spb;

    prep_combine<<<128, 128, 0, stream>>>(w_sc, b_sc, w_out, b_out, wsc2, bout2);
    prep_pack<<<6, 256, 0, stream>>>(w_theta, w_phi, w_g, w_out, wsc2, packs);
    cab_main<<<grid, 1024, 0, stream>>>(x, b_theta, b_phi, b_g, packs, bout2, out, NS, spb);
}

// Round 9
// 174.774 us; speedup vs baseline: 1.6476x; 1.0242x over previous
//
#include <hip/hip_runtime.h>

// ContextAttentionBlock fused kernel for gfx950.
// Per (b,h) row-strip (2048 strips of [128x128]): everything in LDS with
// bf16 MFMA (32x32x16), fp32 accum. Shortcut conv folded into the output
// projection (w_sc @ Wo1 precomputed).
//
// Notes (measured R1-R8):
//  - hipcc allocates VGPR = 65536/blockDim (512->128, 1024->64). Fit the cap.
//  - unroll 2 on kk loops is the spill sweet spot (R6); unroll 4 re-spills (R7).
//  - 1024 thr / 16 waves / one 32x32 tile per wave: ~60 VGPR live, 4 waves/SIMD
//    (R8: 242->162us, occupancy 44%).
//  - R9: native __bf16 casts (compiler emits v_cvt_pk_bf16_f32) instead of
//    hand-rolled round-to-nearest-even bit math (~5 VALU ops/value).
//  - LDS rotation: FPT region is dead after phase C, so next strip's x is
//    staged there; XB/FPT roles swap each iteration.

typedef __bf16 bf16x8 __attribute__((ext_vector_type(8)));
typedef __bf16 bf16x4 __attribute__((ext_vector_type(4)));
typedef float f32x16 __attribute__((ext_vector_type(16)));

// byte offset inside a [128][128] bf16 buffer (256 B rows).
// XOR of row bits into byte-offset bits 4..7 spreads 32-consecutive-row
// column accesses over 16 distinct 16B slots (R2: conflicts 13.1M -> 2.6M).
__device__ __forceinline__ int swz(int row, int cb) {
    return (row << 8) + (cb ^ ((row & 15) << 4));
}
__device__ __forceinline__ float sigm(float t) {
    return 1.0f / (1.0f + __expf(-t));
}

// ---------------- pre-pass 1: combined shortcut weight -----------------
__global__ void prep_combine(const float* __restrict__ w_sc,
                             const float* __restrict__ b_sc,
                             const float* __restrict__ w_out,
                             const float* __restrict__ b_out,
                             float* __restrict__ wsc2,
                             float* __restrict__ bout2) {
    int k = blockIdx.x;      // 0..127
    int n = threadIdx.x;     // 0..127
    float acc = 0.f;
    for (int c = 0; c < 128; ++c)
        acc += w_sc[k * 128 + c] * w_out[(128 + c) * 128 + n];
    wsc2[k * 128 + n] = acc;
    if (k == 0) {
        float b = b_out[n];
        for (int c = 0; c < 128; ++c)
            b += b_sc[c] * w_out[(128 + c) * 128 + n];
        bout2[n] = b;
    }
}

// ---------------- pre-pass 2: pack weights into MFMA B-frag order ------
__global__ void prep_pack(const float* __restrict__ wth,
                          const float* __restrict__ wph,
                          const float* __restrict__ wg,
                          const float* __restrict__ wout,
                          const float* __restrict__ wsc2,
                          __bf16* __restrict__ packs) {
    int m = blockIdx.x;
    const float* src;
    int rowoff = 0;
    if (m == 0) src = wth;
    else if (m == 1) src = wph;
    else if (m == 2) src = wg;
    else if (m == 3) { src = wout; rowoff = 0; }
    else if (m == 4) { src = wout; rowoff = 256; }
    else src = wsc2;
    __bf16* dst = packs + m * 16384;
    for (int i = threadIdx.x; i < 16384; i += blockDim.x) {
        int j = i & 7;
        int lane = (i >> 3) & 63;
        int kk = (i >> 9) & 7;
        int nt = i >> 12;
        int k = kk * 16 + ((lane >> 5) << 3) + j;
        int n = nt * 32 + (lane & 31);
        dst[i] = (__bf16)(src[(rowoff + k) * 128 + n]);
    }
}

// ---------------- main fused kernel ------------------------------------
#define FPB 32768
#define FGT 98304

__global__ __launch_bounds__(1024, 1)
void cab_main(const float* __restrict__ x,
              const float* __restrict__ b_theta,
              const float* __restrict__ b_phi,
              const float* __restrict__ b_g,
              const __bf16* __restrict__ packs,
              const float* __restrict__ bout2,
              float* __restrict__ out,
              int nstrips, int spb) {
    __shared__ __align__(16) char lds[131072];

    const int tid = threadIdx.x;
    const int l   = tid & 63;
    const int wv  = tid >> 6;          // 0..15
    const int ct  = wv & 3;            // tile col (0..3)
    const int rt  = wv >> 2;           // tile row (0..3)
    const int ln  = l & 31;
    const int lh  = l >> 5;
    const int colg = ct * 32 + ln;     // this wave's output column
    const int m0   = rt * 32;          // this wave's output row base

    const __bf16* pTH = packs;
    const __bf16* pPH = packs + 16384;
    const __bf16* pG  = packs + 2 * 16384;
    const __bf16* pO0 = packs + 3 * 16384;
    const __bf16* pO2 = packs + 4 * 16384;
    const __bf16* pS2 = packs + 5 * 16384;

    const float biasTH = b_theta[colg];
    const float biasPH = b_phi[colg];
    const float biasG  = b_g[colg];
    const float biasO  = bout2[colg];

    const int s0 = blockIdx.x * spb;
    if (s0 >= nstrips) return;
    const float4* x4 = (const float4*)x;

    // staging geometry (1024 thr): idx = q*1024+tid -> row = q*32 + (tid>>5),
    // byte col = (tid&31)*8. Chunk c covers q = {2c, 2c+1} (rows c*64..c*64+63).
    const int srow = tid >> 5;          // 0..31
    const int scb  = (tid & 31) * 8;    // byte col

    float4 pf[2];

    // initial full stage of strip s0 into region 0
    {
        long base = (long)s0 * 4096;
#pragma unroll
        for (int c = 0; c < 2; ++c) {
#pragma unroll
            for (int q = 0; q < 2; ++q) pf[q] = x4[base + (c * 2 + q) * 1024 + tid];
#pragma unroll
            for (int q = 0; q < 2; ++q) {
                int row = (c * 2 + q) * 32 + srow;
                bf16x4 v;
                v[0] = (__bf16)pf[q].x; v[1] = (__bf16)pf[q].y;
                v[2] = (__bf16)pf[q].z; v[3] = (__bf16)pf[q].w;
                *(bf16x4*)(lds + swz(row, scb)) = v;
            }
        }
    }
    __syncthreads();

    for (int it = 0; it < spb; ++it) {
        const int s = s0 + it;
        // rotating roles: XB holds current x; FPT region doubles as next-XB
        const int XBo  = (it & 1) ? 65536 : 0;
        const int FPTo = 65536 - XBo;
        f32x16 acc;

        // ===== B1: f_phi = xb @ w_phi + b  -> FPB (row-major) + FPT ([c][w])
#pragma unroll
        for (int i = 0; i < 16; ++i) acc[i] = 0.f;
#pragma unroll 2
        for (int kk = 0; kk < 8; ++kk) {
            bf16x8 b = *(const bf16x8*)(pPH + (((ct * 8 + kk) * 64 + l) << 3));
            bf16x8 a = *(const bf16x8*)(lds + XBo + swz(m0 + ln, kk * 32 + lh * 16));
            acc = __builtin_amdgcn_mfma_f32_32x32x16_bf16(a, b, acc, 0, 0, 0);
        }
#pragma unroll
        for (int r = 0; r < 16; ++r) {
            int row = m0 + (r & 3) + ((r >> 2) << 3) + (lh << 2);
            *(__bf16*)(lds + FPB + swz(row, colg * 2)) = (__bf16)(acc[r] + biasPH);
        }
#pragma unroll
        for (int q = 0; q < 4; ++q) {
            int w0 = m0 + (q << 3) + (lh << 2);
            bf16x4 v;
#pragma unroll
            for (int e = 0; e < 4; ++e) v[e] = (__bf16)(acc[q * 4 + e] + biasPH);
            *(bf16x4*)(lds + FPTo + swz(colg, w0 * 2)) = v;
        }

        // ===== B2: f_g = xb @ w_g + b -> FGT ([c][w])
#pragma unroll
        for (int i = 0; i < 16; ++i) acc[i] = 0.f;
#pragma unroll 2
        for (int kk = 0; kk < 8; ++kk) {
            bf16x8 b = *(const bf16x8*)(pG + (((ct * 8 + kk) * 64 + l) << 3));
            bf16x8 a = *(const bf16x8*)(lds + XBo + swz(m0 + ln, kk * 32 + lh * 16));
            acc = __builtin_amdgcn_mfma_f32_32x32x16_bf16(a, b, acc, 0, 0, 0);
        }
#pragma unroll
        for (int q = 0; q < 4; ++q) {
            int w0 = m0 + (q << 3) + (lh << 2);
            bf16x4 v;
#pragma unroll
            for (int e = 0; e < 4; ++e) v[e] = (__bf16)(acc[q * 4 + e] + biasG);
            *(bf16x4*)(lds + FGT + swz(colg, w0 * 2)) = v;
        }
        __syncthreads();   // (1) FPB/FPT/FGT ready

        // issue chunk0 of next strip's x (latency hidden by D/V/B3/C)
        if (it + 1 < spb) {
            long base = (long)(s + 1) * 4096;
#pragma unroll
            for (int q = 0; q < 2; ++q) pf[q] = x4[base + q * 1024 + tid];
        }

        // ===== D: v-logits  D[j][i] = sum_w fp[w][j] * fg[w][i]
#pragma unroll
        for (int i = 0; i < 16; ++i) acc[i] = 0.f;
#pragma unroll 2
        for (int kk = 0; kk < 8; ++kk) {
            bf16x8 b = *(const bf16x8*)(lds + FGT + swz(colg, kk * 32 + lh * 16));
            bf16x8 a = *(const bf16x8*)(lds + FPTo + swz(m0 + ln, kk * 32 + lh * 16));
            acc = __builtin_amdgcn_mfma_f32_32x32x16_bf16(a, b, acc, 0, 0, 0);
        }
        __syncthreads();   // (2) all D reads of FPT/FGT done

        // V epilogue: V[i][j] = sigm(D[j][i]) * x[i][j]  -> overwrite FGT
#pragma unroll
        for (int q = 0; q < 4; ++q) {
            int j0 = m0 + (q << 3) + (lh << 2);
            bf16x4 xv = *(const bf16x4*)(lds + XBo + swz(colg, j0 * 2));
            bf16x4 v;
#pragma unroll
            for (int e = 0; e < 4; ++e)
                v[e] = (__bf16)(sigm(acc[q * 4 + e]) * (float)xv[e]);
            *(bf16x4*)(lds + FGT + swz(colg, j0 * 2)) = v;
        }

        // ===== B3: f_theta = xb @ w_theta + b -> FPT slot (row-major "ftb")
#pragma unroll
        for (int i = 0; i < 16; ++i) acc[i] = 0.f;
#pragma unroll 2
        for (int kk = 0; kk < 8; ++kk) {
            bf16x8 b = *(const bf16x8*)(pTH + (((ct * 8 + kk) * 64 + l) << 3));
            bf16x8 a = *(const bf16x8*)(lds + XBo + swz(m0 + ln, kk * 32 + lh * 16));
            acc = __builtin_amdgcn_mfma_f32_32x32x16_bf16(a, b, acc, 0, 0, 0);
        }
#pragma unroll
        for (int r = 0; r < 16; ++r) {
            int row = m0 + (r & 3) + ((r >> 2) << 3) + (lh << 2);
            *(__bf16*)(lds + FPTo + swz(row, colg * 2)) = (__bf16)(acc[r] + biasTH);
        }
        __syncthreads();   // (3) V + ftb ready

        // ===== C: h-logits  D[v][w] = sum_c ft[v][c] * fp[w][c]
#pragma unroll
        for (int i = 0; i < 16; ++i) acc[i] = 0.f;
#pragma unroll 2
        for (int kk = 0; kk < 8; ++kk) {
            bf16x8 b = *(const bf16x8*)(lds + FPB + swz(colg, kk * 32 + lh * 16));
            bf16x8 a = *(const bf16x8*)(lds + FPTo + swz(m0 + ln, kk * 32 + lh * 16));
            acc = __builtin_amdgcn_mfma_f32_32x32x16_bf16(a, b, acc, 0, 0, 0);
        }
        __syncthreads();   // (4) all C reads of FPB/FPT done; FPT region now free

        // write chunk0 of next x into FPT region (= next iteration's XB)
        if (it + 1 < spb) {
#pragma unroll
            for (int q = 0; q < 2; ++q) {
                int row = q * 32 + srow;     // rows 0..63
                bf16x4 v;
                v[0] = (__bf16)pf[q].x; v[1] = (__bf16)pf[q].y;
                v[2] = (__bf16)pf[q].z; v[3] = (__bf16)pf[q].w;
                *(bf16x4*)(lds + FPTo + swz(row, scb)) = v;
            }
            // issue chunk1 loads (latency hidden by H epilogue + E)
            long base = (long)(s + 1) * 4096;
#pragma unroll
            for (int q = 0; q < 2; ++q) pf[q] = x4[base + (2 + q) * 1024 + tid];
        }

        // H epilogue: H[w][v] = sigm(D[v][w]) * x[w][v] -> overwrite FPB
#pragma unroll
        for (int q = 0; q < 4; ++q) {
            int v0 = m0 + (q << 3) + (lh << 2);
            bf16x4 xv = *(const bf16x4*)(lds + XBo + swz(colg, v0 * 2));
            bf16x4 v;
#pragma unroll
            for (int e = 0; e < 4; ++e)
                v[e] = (__bf16)(sigm(acc[q * 4 + e]) * (float)xv[e]);
            *(bf16x4*)(lds + FPB + swz(colg, v0 * 2)) = v;
        }
        __syncthreads();   // (5) H ready

        // ===== E: out = H @ Wo0 + V @ Wo2 + xb @ Wsc2 + bout2
#pragma unroll
        for (int i = 0; i < 16; ++i) acc[i] = 0.f;
#pragma unroll 2
        for (int kk = 0; kk < 8; ++kk) {
            bf16x8 b = *(const bf16x8*)(pO0 + (((ct * 8 + kk) * 64 + l) << 3));
            bf16x8 a = *(const bf16x8*)(lds + FPB + swz(m0 + ln, kk * 32 + lh * 16));
            acc = __builtin_amdgcn_mfma_f32_32x32x16_bf16(a, b, acc, 0, 0, 0);
        }
#pragma unroll 2
        for (int kk = 0; kk < 8; ++kk) {
            bf16x8 b = *(const bf16x8*)(pO2 + (((ct * 8 + kk) * 64 + l) << 3));
            bf16x8 a = *(const bf16x8*)(lds + FGT + swz(m0 + ln, kk * 32 + lh * 16));
            acc = __builtin_amdgcn_mfma_f32_32x32x16_bf16(a, b, acc, 0, 0, 0);
        }
#pragma unroll 2
        for (int kk = 0; kk < 8; ++kk) {
            bf16x8 b = *(const bf16x8*)(pS2 + (((ct * 8 + kk) * 64 + l) << 3));
            bf16x8 a = *(const bf16x8*)(lds + XBo + swz(m0 + ln, kk * 32 + lh * 16));
            acc = __builtin_amdgcn_mfma_f32_32x32x16_bf16(a, b, acc, 0, 0, 0);
        }
        {
            long obase = (long)s * 16384;
#pragma unroll
            for (int r = 0; r < 16; ++r) {
                int row = m0 + (r & 3) + ((r >> 2) << 3) + (lh << 2);
                out[obase + row * 128 + colg] = acc[r] + biasO;
            }
        }

        // write chunk1 of next x into FPT region (rows 64..127)
        if (it + 1 < spb) {
#pragma unroll
            for (int q = 0; q < 2; ++q) {
                int row = 64 + q * 32 + srow;
                bf16x4 v;
                v[0] = (__bf16)pf[q].x; v[1] = (__bf16)pf[q].y;
                v[2] = (__bf16)pf[q].z; v[3] = (__bf16)pf[q].w;
                *(bf16x4*)(lds + FPTo + swz(row, scb)) = v;
            }
        }
        __syncthreads();   // (6) E's XB reads + next-x staging done
    }
}

extern "C" void kernel_launch(void* const* d_in, const int* in_sizes, int n_in,
                              void* d_out, int out_size, void* d_ws, size_t ws_size,
                              hipStream_t stream) {
    const float* x       = (const float*)d_in[0];
    const float* w_theta = (const float*)d_in[1];
    const float* b_theta = (const float*)d_in[2];
    const float* w_phi   = (const float*)d_in[3];
    const float* b_phi   = (const float*)d_in[4];
    const float* w_g     = (const float*)d_in[5];
    const float* b_g     = (const float*)d_in[6];
    const float* w_sc    = (const float*)d_in[7];
    const float* b_sc    = (const float*)d_in[8];
    const float* w_out   = (const float*)d_in[9];
    const float* b_out   = (const float*)d_in[10];
    float* out = (float*)d_out;

    float* wsc2 = (float*)d_ws;                                        // 128*128 f32
    __bf16* packs = (__bf16*)((char*)d_ws + 65536);                    // 6*16384 bf16
    float* bout2 = (float*)((char*)d_ws + 65536 + 6 * 16384 * 2);      // 128 f32

    int NS = in_sizes[0] / 16384;   // 2048 strips
    int spb = NS / 256;             // strips per block (8)
    if (spb < 1) spb = 1;
    int grid = (NS + spb - 1) / spb;

    prep_combine<<<128, 128, 0, stream>>>(w_sc, b_sc, w_out, b_out, wsc2, bout2);
    prep_pack<<<6, 256, 0, stream>>>(w_theta, w_phi, w_g, w_out, wsc2, packs);
    cab_main<<<grid, 1024, 0, stream>>>(x, b_theta, b_phi, b_g, packs, bout2, out, NS, spb);
}